// Round 16
// baseline (23.240 us; speedup 1.0000x reference)
//
#include <hip/hip_runtime.h>
#include <math.h>

#define B 1024
#define C 512
#define S 32
#define E 128

typedef __attribute__((ext_vector_type(8))) short bf16x8;
typedef __attribute__((ext_vector_type(4))) float f32x4;

// ---------------------------------------------------------------------------
// Workspace layout (float units):
//   xfrag  : bf16 [B/16][4 kt][64 lane][8 j]   @ f0        (65536 f)
//   wfrag  : bf16 [C][4 kt][2 mt][64][8]       @ f65536    (1048576 f)
//   gfrag  : bf16 [C][2 mt][64][8]             @ f1114112  (262144 f)
//   label  : u32 [B]                           @ f1376256  (1024)
//   zlab   : f32 [B]                           @ f1377280  (1024)
//   psum   : f32 [128 cblk][B]                 @ f1378304  (131072)
// Fragment mapping (mfma_f32_16x16x32_bf16 A/B operand):
//   frag[j] = M[row = lane&15][k = 4*(lane>>4) + (j&3) + 16*(j>>2)]
// D mapping: D[row = 4*(lane>>4)+r][col = lane&15]
// z = s*logit in [0, ~8.9] -> exp safe without max-subtraction.
// ---------------------------------------------------------------------------
#define OFF_XFRAG  0
#define OFF_WFRAG  65536
#define OFF_GFRAG  1114112
#define OFF_LABEL  1376256
#define OFF_ZLAB   1377280
#define OFF_PSUM   1378304

__device__ inline unsigned short f2bf(float f) {
    unsigned u = __float_as_uint(f);
    return (unsigned short)((u + 0x7fffu + ((u >> 16) & 1u)) >> 16);
}

// Fused prep: blocks [0,64) = x tiles (16 rows each) + label extraction;
// blocks [64,576) = one class each (normalize W, pack frags, Gram via MFMA).
// Block 0 also zeroes out[0] (k_final atomics accumulate into it later).
__global__ __launch_bounds__(256) void k_prep(const float* __restrict__ x,
                                              const float* __restrict__ W,
                                              const float* __restrict__ y,
                                              unsigned short* __restrict__ xfrag,
                                              unsigned short* __restrict__ wfrag,
                                              unsigned short* __restrict__ gfrag,
                                              unsigned int* __restrict__ label,
                                              float* __restrict__ out) {
    __shared__ float sM[32][132];
    __shared__ int4 wf[512];
    int t = threadIdx.x;
    int blk = blockIdx.x;
    if (blk == 0 && t == 0) out[0] = 0.f;
    if (blk < 64) {
        const float4* gx = reinterpret_cast<const float4*>(x + (size_t)blk * 16 * 128);
        #pragma unroll
        for (int i = 0; i < 2; ++i) {
            int ci = t + 256 * i;
            *reinterpret_cast<float4*>(&sM[ci >> 5][(ci & 31) << 2]) = gx[ci];
        }
        __syncthreads();
        int r = t >> 4, j = t & 15;
        float ss = 0.f;
        #pragma unroll
        for (int i = 0; i < 8; ++i) { float v = sM[r][j + 16 * i]; ss += v * v; }
        #pragma unroll
        for (int m = 1; m < 16; m <<= 1) ss += __shfl_xor(ss, m, 16);
        float sc = 1.0f / fmaxf(sqrtf(ss), 1e-12f);
        #pragma unroll
        for (int i = 0; i < 8; ++i) sM[r][j + 16 * i] *= sc;
        __syncthreads();
        int kt = t >> 6, lane = t & 63;
        int row = lane & 15, k0 = kt * 32 + 4 * (lane >> 4);
        union { unsigned short u[8]; int4 v; } pk;
        #pragma unroll
        for (int g = 0; g < 2; ++g) {
            float4 rv = *reinterpret_cast<const float4*>(&sM[row][k0 + 16 * g]);
            pk.u[4 * g + 0] = f2bf(rv.x); pk.u[4 * g + 1] = f2bf(rv.y);
            pk.u[4 * g + 2] = f2bf(rv.z); pk.u[4 * g + 3] = f2bf(rv.w);
        }
        reinterpret_cast<int4*>(xfrag)[(size_t)blk * 256 + t] = pk.v;
        // ---- label extraction for rows blk*16 .. blk*16+15 ----
        const float4* yr = reinterpret_cast<const float4*>(y + (size_t)(blk * 16 + r) * C);
        int idx = 0;
        #pragma unroll
        for (int k = 0; k < 8; ++k) {
            float4 v = yr[j + 16 * k];
            int base = (j + 16 * k) * 4;
            if (v.x > 0.5f) idx = base;
            if (v.y > 0.5f) idx = base + 1;
            if (v.z > 0.5f) idx = base + 2;
            if (v.w > 0.5f) idx = base + 3;
        }
        #pragma unroll
        for (int m = 1; m < 16; m <<= 1) idx = max(idx, __shfl_xor(idx, m, 16));
        if (j == 0) label[blk * 16 + r] = (unsigned int)idx;
    } else {
        int c = blk - 64;
        const float4* gw = reinterpret_cast<const float4*>(W + (size_t)c * S * E);
        #pragma unroll
        for (int i = 0; i < 4; ++i) {
            int ci = t + 256 * i;
            *reinterpret_cast<float4*>(&sM[ci >> 5][(ci & 31) << 2]) = gw[ci];
        }
        __syncthreads();
        int r = t >> 3, j = t & 7;
        float ss = 0.f;
        #pragma unroll
        for (int i = 0; i < 16; ++i) { float v = sM[r][j + 8 * i]; ss += v * v; }
        #pragma unroll
        for (int m = 1; m < 8; m <<= 1) ss += __shfl_xor(ss, m, 8);
        float sc = 1.0f / fmaxf(sqrtf(ss), 1e-12f);
        #pragma unroll
        for (int i = 0; i < 16; ++i) sM[r][j + 8 * i] *= sc;
        __syncthreads();
        int4* gwf = reinterpret_cast<int4*>(wfrag) + (size_t)c * 512;
        #pragma unroll
        for (int ci = t; ci < 512; ci += 256) {
            int kt = ci >> 7, mt = (ci >> 6) & 1, ln = ci & 63;
            int srow = mt * 16 + (ln & 15), k0 = kt * 32 + 4 * (ln >> 4);
            union { unsigned short u[8]; int4 v; } pk;
            #pragma unroll
            for (int g = 0; g < 2; ++g) {
                float4 rv = *reinterpret_cast<const float4*>(&sM[srow][k0 + 16 * g]);
                pk.u[4 * g + 0] = f2bf(rv.x); pk.u[4 * g + 1] = f2bf(rv.y);
                pk.u[4 * g + 2] = f2bf(rv.z); pk.u[4 * g + 3] = f2bf(rv.w);
            }
            wf[ci] = pk.v;
            gwf[ci] = pk.v;
        }
        __syncthreads();
        int w = t >> 6, lane = t & 63;
        if (w < 2) {
            const bf16x8* f = reinterpret_cast<const bf16x8*>(wf);
            f32x4 d0 = {0.f, 0.f, 0.f, 0.f}, d1 = d0;
            #pragma unroll
            for (int kt = 0; kt < 4; ++kt) {
                bf16x8 bnt = f[kt * 128 + w * 64 + lane];
                bf16x8 a0  = f[kt * 128 + lane];
                bf16x8 a1  = f[kt * 128 + 64 + lane];
                d0 = __builtin_amdgcn_mfma_f32_16x16x32_bf16(a0, bnt, d0, 0, 0, 0);
                d1 = __builtin_amdgcn_mfma_f32_16x16x32_bf16(a1, bnt, d1, 0, 0, 0);
            }
            union { unsigned short u[8]; int4 v; } pk;
            #pragma unroll
            for (int r2 = 0; r2 < 4; ++r2) {
                pk.u[r2]     = f2bf(d0[r2]);
                pk.u[r2 + 4] = f2bf(d1[r2]);
            }
            reinterpret_cast<int4*>(gfrag)[(size_t)c * 128 + w * 64 + lane] = pk.v;
        }
    }
}

// Fused logits+softmax-partials. Grid (128 class-groups, 16 b-tiles) = 2048
// blocks -> 8 blocks/CU, 32 waves/CU. One 4-class wave tile per block (no
// inner loop). VGPR footprint is naturally 64 (8 waves/SIMD x 64 = 512 = full
// file) -- launch_bounds stays (256,4): round-13 lesson is that FORCING 8
// makes the allocator target 32 VGPR and spill; the minimum-4 declaration
// keeps VGPR=64 while the hardware schedules 8 blocks/CU (LDS 8x17KB=136KB).
// XCD pinning (T1) preserved: 128 % 8 == 0 -> bid%8 == cy%8; 64 classes/XCD
// = 640KB wfrag+gfrag slice, per-XCD-L2-resident.
__global__ __launch_bounds__(256, 4) void k_logits_fused(const unsigned short* __restrict__ xfrag,
                                                         const unsigned short* __restrict__ wfrag,
                                                         const unsigned short* __restrict__ gfrag,
                                                         const unsigned int* __restrict__ label,
                                                         const float* __restrict__ s_ptr,
                                                         float* __restrict__ psum,
                                                         float* __restrict__ zlab) {
    __shared__ int4 smem[1024];       // 16KB X tile
    __shared__ float s_ps[4][4][16];  // per-wave psum partials
    int t = threadIdx.x;
    int w = t >> 6, lane = t & 63;
    int cy = blockIdx.x;              // class-group (XCD-pinned)
    int b0 = blockIdx.y * 64;         // b-tile
    int c = cy * 4 + w;
    float s = s_ptr[0];

    const int4* gX = reinterpret_cast<const int4*>(xfrag) + (size_t)(b0 >> 4) * 256;
    #pragma unroll
    for (int i = 0; i < 4; ++i) smem[t + 256 * i] = gX[t + 256 * i];
    int labl[4];
    if (lane < 16) {
        #pragma unroll
        for (int bt = 0; bt < 4; ++bt) labl[bt] = (int)label[b0 + bt * 16 + lane];
    }
    __syncthreads();
    const bf16x8* fX = reinterpret_cast<const bf16x8*>(smem);  // [bt][kt][64]

    const bf16x8* gW = reinterpret_cast<const bf16x8*>(wfrag) + (size_t)c * 512;
    const bf16x8* gG = reinterpret_cast<const bf16x8*>(gfrag) + (size_t)c * 128;
    bf16x8 a[4][2];
    #pragma unroll
    for (int kt = 0; kt < 4; ++kt) {
        a[kt][0] = gW[kt * 128 + lane];
        a[kt][1] = gW[kt * 128 + 64 + lane];
    }
    f32x4 acc[2][4];
    #pragma unroll
    for (int m = 0; m < 2; ++m)
        #pragma unroll
        for (int bt = 0; bt < 4; ++bt) acc[m][bt] = (f32x4){0.f, 0.f, 0.f, 0.f};
    #pragma unroll
    for (int kt = 0; kt < 4; ++kt) {
        #pragma unroll
        for (int bt = 0; bt < 4; ++bt) {
            bf16x8 bv = fX[bt * 256 + kt * 64 + lane];
            acc[0][bt] = __builtin_amdgcn_mfma_f32_16x16x32_bf16(a[kt][0], bv, acc[0][bt], 0, 0, 0);
            acc[1][bt] = __builtin_amdgcn_mfma_f32_16x16x32_bf16(a[kt][1], bv, acc[1][bt], 0, 0, 0);
        }
    }
    bf16x8 g0 = gG[lane];
    bf16x8 g1 = gG[64 + lane];

    float psacc[4] = {0.f, 0.f, 0.f, 0.f};
    #pragma unroll
    for (int bt = 0; bt < 4; ++bt) {
        union { unsigned short u[8]; bf16x8 v; } p;
        #pragma unroll
        for (int r = 0; r < 4; ++r) {
            p.u[r]     = f2bf(acc[0][bt][r]);
            p.u[r + 4] = f2bf(acc[1][bt][r]);
        }
        f32x4 h0 = {0.f, 0.f, 0.f, 0.f}, h1 = h0;
        h0 = __builtin_amdgcn_mfma_f32_16x16x32_bf16(g0, p.v, h0, 0, 0, 0);
        h1 = __builtin_amdgcn_mfma_f32_16x16x32_bf16(g1, p.v, h1, 0, 0, 0);
        float n = 0.f, q = 0.f;
        #pragma unroll
        for (int r = 0; r < 4; ++r) {
            n += acc[0][bt][r] * acc[0][bt][r] + acc[1][bt][r] * acc[1][bt][r];
            q += acc[0][bt][r] * h0[r] + acc[1][bt][r] * h1[r];
        }
        n += __shfl_xor(n, 16); n += __shfl_xor(n, 32);
        q += __shfl_xor(q, 16); q += __shfl_xor(q, 32);
        if (lane < 16) {
            float z = s * (n / fmaxf(sqrtf(q), 1e-12f));
            psacc[bt] = __expf(z);
            if (labl[bt] == c) zlab[b0 + bt * 16 + lane] = z;
        }
    }
    if (lane < 16) {
        #pragma unroll
        for (int bt = 0; bt < 4; ++bt) s_ps[w][bt][lane] = psacc[bt];
    }
    __syncthreads();
    if (t < 64) {
        int bt = t >> 4, l = t & 15;
        float v = s_ps[0][bt][l] + s_ps[1][bt][l] + s_ps[2][bt][l] + s_ps[3][bt][l];
        psum[(size_t)cy * B + b0 + bt * 16 + l] = v;
    }
}

// Merged final: 16 blocks; block handles 64 rows. Wave w sums partials
// p in [32w, 32w+32) (wave-coalesced 256B reads), LDS combine, and the
// block's partial of mean(log(se) - zlab) is atomicAdd'ed into out[0]
// (16 atomics total; out zeroed by k_prep).
__global__ __launch_bounds__(256) void k_final(const float* __restrict__ psum,
                                               const float* __restrict__ zlab,
                                               float* __restrict__ out) {
    __shared__ float sacc[4][64];
    int t = threadIdx.x, w = t >> 6, lane = t & 63;
    int row = blockIdx.x * 64 + lane;
    float se = 0.f;
    #pragma unroll
    for (int i = 0; i < 32; ++i) {
        int p = w * 32 + i;
        se += psum[(size_t)p * B + row];
    }
    sacc[w][lane] = se;
    __syncthreads();
    if (w == 0) {
        float tot = sacc[0][lane] + sacc[1][lane] + sacc[2][lane] + sacc[3][lane];
        float l = logf(tot) - zlab[row];
        #pragma unroll
        for (int off = 1; off < 64; off <<= 1) l += __shfl_xor(l, off);
        if (lane == 0) atomicAdd(out, l * (1.0f / (float)B));
    }
}

extern "C" void kernel_launch(void* const* d_in, const int* in_sizes, int n_in,
                              void* d_out, int out_size, void* d_ws, size_t ws_size,
                              hipStream_t stream) {
    const float* x = (const float*)d_in[0];
    const float* y = (const float*)d_in[1];
    const float* W = (const float*)d_in[2];
    const float* s = (const float*)d_in[3];
    float* ws = (float*)d_ws;
    float* out = (float*)d_out;

    unsigned short* xfrag = (unsigned short*)(ws + OFF_XFRAG);
    unsigned short* wfrag = (unsigned short*)(ws + OFF_WFRAG);
    unsigned short* gfrag = (unsigned short*)(ws + OFF_GFRAG);
    unsigned int* label = (unsigned int*)(ws + OFF_LABEL);
    float* zlab = ws + OFF_ZLAB;
    float* psum = ws + OFF_PSUM;

    k_prep<<<576, 256, 0, stream>>>(x, W, y, xfrag, wfrag, gfrag, label, out);
    // grid.x = class-group (XCD-pinned), grid.y = b-tile
    k_logits_fused<<<dim3(C / 4, B / 64), 256, 0, stream>>>(xfrag, wfrag, gfrag,
                                                            label, s, psum, zlab);
    k_final<<<16, 256, 0, stream>>>(psum, zlab, out);
}

// Round 17
// 22.223 us; speedup vs baseline: 1.0457x; 1.0457x over previous
//
#include <hip/hip_runtime.h>
#include <math.h>

#define B 1024
#define C 512
#define S 32
#define E 128

typedef __attribute__((ext_vector_type(8))) short bf16x8;
typedef __attribute__((ext_vector_type(4))) float f32x4;

// ---------------------------------------------------------------------------
// Workspace layout (float units):
//   xfrag  : bf16 [B/16][4 kt][64 lane][8 j]   @ f0        (65536 f)
//   wfrag  : bf16 [C][4 kt][2 mt][64][8]       @ f65536    (1048576 f)
//   gfrag  : bf16 [C][2 mt][64][8]             @ f1114112  (262144 f)
//   label  : u32 [B]                           @ f1376256  (1024)
//   zlab   : f32 [B]                           @ f1377280  (1024)
//   psum   : f32 [64 cblk][B]                  @ f1378304  (65536)
// Fragment mapping (mfma_f32_16x16x32_bf16 A/B operand):
//   frag[j] = M[row = lane&15][k = 4*(lane>>4) + (j&3) + 16*(j>>2)]
// D mapping: D[row = 4*(lane>>4)+r][col = lane&15]
// z = s*logit in [0, ~8.9] -> exp safe without max-subtraction.
// ---------------------------------------------------------------------------
#define OFF_XFRAG  0
#define OFF_WFRAG  65536
#define OFF_GFRAG  1114112
#define OFF_LABEL  1376256
#define OFF_ZLAB   1377280
#define OFF_PSUM   1378304

__device__ inline unsigned short f2bf(float f) {
    unsigned u = __float_as_uint(f);
    return (unsigned short)((u + 0x7fffu + ((u >> 16) & 1u)) >> 16);
}

// Fused prep: blocks [0,64) = x tiles (16 rows each) + label extraction;
// blocks [64,576) = one class each (normalize W, pack frags, Gram via MFMA).
// Block 0 also zeroes out[0] (k_final atomics accumulate into it later).
__global__ __launch_bounds__(256) void k_prep(const float* __restrict__ x,
                                              const float* __restrict__ W,
                                              const float* __restrict__ y,
                                              unsigned short* __restrict__ xfrag,
                                              unsigned short* __restrict__ wfrag,
                                              unsigned short* __restrict__ gfrag,
                                              unsigned int* __restrict__ label,
                                              float* __restrict__ out) {
    __shared__ float sM[32][132];
    __shared__ int4 wf[512];
    int t = threadIdx.x;
    int blk = blockIdx.x;
    if (blk == 0 && t == 0) out[0] = 0.f;
    if (blk < 64) {
        const float4* gx = reinterpret_cast<const float4*>(x + (size_t)blk * 16 * 128);
        #pragma unroll
        for (int i = 0; i < 2; ++i) {
            int ci = t + 256 * i;
            *reinterpret_cast<float4*>(&sM[ci >> 5][(ci & 31) << 2]) = gx[ci];
        }
        __syncthreads();
        int r = t >> 4, j = t & 15;
        float ss = 0.f;
        #pragma unroll
        for (int i = 0; i < 8; ++i) { float v = sM[r][j + 16 * i]; ss += v * v; }
        #pragma unroll
        for (int m = 1; m < 16; m <<= 1) ss += __shfl_xor(ss, m, 16);
        float sc = 1.0f / fmaxf(sqrtf(ss), 1e-12f);
        #pragma unroll
        for (int i = 0; i < 8; ++i) sM[r][j + 16 * i] *= sc;
        __syncthreads();
        int kt = t >> 6, lane = t & 63;
        int row = lane & 15, k0 = kt * 32 + 4 * (lane >> 4);
        union { unsigned short u[8]; int4 v; } pk;
        #pragma unroll
        for (int g = 0; g < 2; ++g) {
            float4 rv = *reinterpret_cast<const float4*>(&sM[row][k0 + 16 * g]);
            pk.u[4 * g + 0] = f2bf(rv.x); pk.u[4 * g + 1] = f2bf(rv.y);
            pk.u[4 * g + 2] = f2bf(rv.z); pk.u[4 * g + 3] = f2bf(rv.w);
        }
        reinterpret_cast<int4*>(xfrag)[(size_t)blk * 256 + t] = pk.v;
        // ---- label extraction for rows blk*16 .. blk*16+15 ----
        const float4* yr = reinterpret_cast<const float4*>(y + (size_t)(blk * 16 + r) * C);
        int idx = 0;
        #pragma unroll
        for (int k = 0; k < 8; ++k) {
            float4 v = yr[j + 16 * k];
            int base = (j + 16 * k) * 4;
            if (v.x > 0.5f) idx = base;
            if (v.y > 0.5f) idx = base + 1;
            if (v.z > 0.5f) idx = base + 2;
            if (v.w > 0.5f) idx = base + 3;
        }
        #pragma unroll
        for (int m = 1; m < 16; m <<= 1) idx = max(idx, __shfl_xor(idx, m, 16));
        if (j == 0) label[blk * 16 + r] = (unsigned int)idx;
    } else {
        int c = blk - 64;
        const float4* gw = reinterpret_cast<const float4*>(W + (size_t)c * S * E);
        #pragma unroll
        for (int i = 0; i < 4; ++i) {
            int ci = t + 256 * i;
            *reinterpret_cast<float4*>(&sM[ci >> 5][(ci & 31) << 2]) = gw[ci];
        }
        __syncthreads();
        int r = t >> 3, j = t & 7;
        float ss = 0.f;
        #pragma unroll
        for (int i = 0; i < 16; ++i) { float v = sM[r][j + 8 * i]; ss += v * v; }
        #pragma unroll
        for (int m = 1; m < 8; m <<= 1) ss += __shfl_xor(ss, m, 8);
        float sc = 1.0f / fmaxf(sqrtf(ss), 1e-12f);
        #pragma unroll
        for (int i = 0; i < 16; ++i) sM[r][j + 8 * i] *= sc;
        __syncthreads();
        int4* gwf = reinterpret_cast<int4*>(wfrag) + (size_t)c * 512;
        #pragma unroll
        for (int ci = t; ci < 512; ci += 256) {
            int kt = ci >> 7, mt = (ci >> 6) & 1, ln = ci & 63;
            int srow = mt * 16 + (ln & 15), k0 = kt * 32 + 4 * (ln >> 4);
            union { unsigned short u[8]; int4 v; } pk;
            #pragma unroll
            for (int g = 0; g < 2; ++g) {
                float4 rv = *reinterpret_cast<const float4*>(&sM[srow][k0 + 16 * g]);
                pk.u[4 * g + 0] = f2bf(rv.x); pk.u[4 * g + 1] = f2bf(rv.y);
                pk.u[4 * g + 2] = f2bf(rv.z); pk.u[4 * g + 3] = f2bf(rv.w);
            }
            wf[ci] = pk.v;
            gwf[ci] = pk.v;
        }
        __syncthreads();
        int w = t >> 6, lane = t & 63;
        if (w < 2) {
            const bf16x8* f = reinterpret_cast<const bf16x8*>(wf);
            f32x4 d0 = {0.f, 0.f, 0.f, 0.f}, d1 = d0;
            #pragma unroll
            for (int kt = 0; kt < 4; ++kt) {
                bf16x8 bnt = f[kt * 128 + w * 64 + lane];
                bf16x8 a0  = f[kt * 128 + lane];
                bf16x8 a1  = f[kt * 128 + 64 + lane];
                d0 = __builtin_amdgcn_mfma_f32_16x16x32_bf16(a0, bnt, d0, 0, 0, 0);
                d1 = __builtin_amdgcn_mfma_f32_16x16x32_bf16(a1, bnt, d1, 0, 0, 0);
            }
            union { unsigned short u[8]; int4 v; } pk;
            #pragma unroll
            for (int r2 = 0; r2 < 4; ++r2) {
                pk.u[r2]     = f2bf(d0[r2]);
                pk.u[r2 + 4] = f2bf(d1[r2]);
            }
            reinterpret_cast<int4*>(gfrag)[(size_t)c * 128 + w * 64 + lane] = pk.v;
        }
    }
}

// Fused logits+softmax-partials. Round-15 config (best: 21.9us): grid
// (64 class-groups, 16 b-tiles) = 1024 blocks -> 4 blocks/CU, VGPR 64,
// XCD-pinned class-groups (bid%8 == cy%8 -> each XCD's 640KB W/G slice is
// L2-resident). Round-17 change: it=0 W/G fragment loads hoisted ABOVE the
// __syncthreads so their L2 latency overlaps the X-staging barrier drain;
// class loop unrolled so it=1 loads schedule into it=0 compute.
__global__ __launch_bounds__(256, 4) void k_logits_fused(const unsigned short* __restrict__ xfrag,
                                                         const unsigned short* __restrict__ wfrag,
                                                         const unsigned short* __restrict__ gfrag,
                                                         const unsigned int* __restrict__ label,
                                                         const float* __restrict__ s_ptr,
                                                         float* __restrict__ psum,
                                                         float* __restrict__ zlab) {
    __shared__ int4 smem[1024];       // 16KB X tile
    __shared__ float s_ps[4][4][16];  // per-wave psum partials
    int t = threadIdx.x;
    int w = t >> 6, lane = t & 63;
    int cy = blockIdx.x;              // class-group (XCD-pinned)
    int b0 = blockIdx.y * 64;         // b-tile
    int cbase = cy * 8;
    float s = s_ptr[0];

    const int4* gX = reinterpret_cast<const int4*>(xfrag) + (size_t)(b0 >> 4) * 256;
    #pragma unroll
    for (int i = 0; i < 4; ++i) smem[t + 256 * i] = gX[t + 256 * i];
    int labl[4];
    if (lane < 16) {
        #pragma unroll
        for (int bt = 0; bt < 4; ++bt) labl[bt] = (int)label[b0 + bt * 16 + lane];
    }
    // hoisted it=0 fragment loads (global->reg, independent of the LDS stage;
    // latency overlaps the barrier's vmcnt drain)
    int c0 = cbase + w;
    bf16x8 a[4][2];
    {
        const bf16x8* gW = reinterpret_cast<const bf16x8*>(wfrag) + (size_t)c0 * 512;
        #pragma unroll
        for (int kt = 0; kt < 4; ++kt) {
            a[kt][0] = gW[kt * 128 + lane];
            a[kt][1] = gW[kt * 128 + 64 + lane];
        }
    }
    bf16x8 g0, g1;
    {
        const bf16x8* gG = reinterpret_cast<const bf16x8*>(gfrag) + (size_t)c0 * 128;
        g0 = gG[lane];
        g1 = gG[64 + lane];
    }
    __syncthreads();
    const bf16x8* fX = reinterpret_cast<const bf16x8*>(smem);  // [bt][kt][64]

    float psacc[4] = {0.f, 0.f, 0.f, 0.f};
    #pragma unroll
    for (int it = 0; it < 2; ++it) {
        int c = cbase + it * 4 + w;
        if (it == 1) {
            const bf16x8* gW = reinterpret_cast<const bf16x8*>(wfrag) + (size_t)c * 512;
            const bf16x8* gG = reinterpret_cast<const bf16x8*>(gfrag) + (size_t)c * 128;
            #pragma unroll
            for (int kt = 0; kt < 4; ++kt) {
                a[kt][0] = gW[kt * 128 + lane];
                a[kt][1] = gW[kt * 128 + 64 + lane];
            }
            g0 = gG[lane];
            g1 = gG[64 + lane];
        }
        f32x4 acc[2][4];
        #pragma unroll
        for (int m = 0; m < 2; ++m)
            #pragma unroll
            for (int bt = 0; bt < 4; ++bt) acc[m][bt] = (f32x4){0.f, 0.f, 0.f, 0.f};
        #pragma unroll
        for (int kt = 0; kt < 4; ++kt) {
            #pragma unroll
            for (int bt = 0; bt < 4; ++bt) {
                bf16x8 bv = fX[bt * 256 + kt * 64 + lane];
                acc[0][bt] = __builtin_amdgcn_mfma_f32_16x16x32_bf16(a[kt][0], bv, acc[0][bt], 0, 0, 0);
                acc[1][bt] = __builtin_amdgcn_mfma_f32_16x16x32_bf16(a[kt][1], bv, acc[1][bt], 0, 0, 0);
            }
        }
        #pragma unroll
        for (int bt = 0; bt < 4; ++bt) {
            union { unsigned short u[8]; bf16x8 v; } p;
            #pragma unroll
            for (int r = 0; r < 4; ++r) {
                p.u[r]     = f2bf(acc[0][bt][r]);
                p.u[r + 4] = f2bf(acc[1][bt][r]);
            }
            f32x4 h0 = {0.f, 0.f, 0.f, 0.f}, h1 = h0;
            h0 = __builtin_amdgcn_mfma_f32_16x16x32_bf16(g0, p.v, h0, 0, 0, 0);
            h1 = __builtin_amdgcn_mfma_f32_16x16x32_bf16(g1, p.v, h1, 0, 0, 0);
            float n = 0.f, q = 0.f;
            #pragma unroll
            for (int r = 0; r < 4; ++r) {
                n += acc[0][bt][r] * acc[0][bt][r] + acc[1][bt][r] * acc[1][bt][r];
                q += acc[0][bt][r] * h0[r] + acc[1][bt][r] * h1[r];
            }
            n += __shfl_xor(n, 16); n += __shfl_xor(n, 32);
            q += __shfl_xor(q, 16); q += __shfl_xor(q, 32);
            if (lane < 16) {
                float z = s * (n / fmaxf(sqrtf(q), 1e-12f));
                psacc[bt] += __expf(z);
                if (labl[bt] == c) zlab[b0 + bt * 16 + lane] = z;
            }
        }
    }
    if (lane < 16) {
        #pragma unroll
        for (int bt = 0; bt < 4; ++bt) s_ps[w][bt][lane] = psacc[bt];
    }
    __syncthreads();
    if (t < 64) {
        int bt = t >> 4, l = t & 15;
        float v = s_ps[0][bt][l] + s_ps[1][bt][l] + s_ps[2][bt][l] + s_ps[3][bt][l];
        psum[(size_t)cy * B + b0 + bt * 16 + l] = v;
    }
}

// Merged final: 16 blocks; block handles 64 rows. Wave w sums partials
// p in [16w, 16w+16) (wave-coalesced 256B reads), LDS combine, and the
// block's partial of mean(log(se) - zlab) is atomicAdd'ed into out[0]
// (16 atomics total; out zeroed by k_prep).
__global__ __launch_bounds__(256) void k_final(const float* __restrict__ psum,
                                               const float* __restrict__ zlab,
                                               float* __restrict__ out) {
    __shared__ float sacc[4][64];
    int t = threadIdx.x, w = t >> 6, lane = t & 63;
    int row = blockIdx.x * 64 + lane;
    float se = 0.f;
    #pragma unroll
    for (int i = 0; i < 16; ++i) {
        int p = w * 16 + i;
        se += psum[(size_t)p * B + row];
    }
    sacc[w][lane] = se;
    __syncthreads();
    if (w == 0) {
        float tot = sacc[0][lane] + sacc[1][lane] + sacc[2][lane] + sacc[3][lane];
        float l = logf(tot) - zlab[row];
        #pragma unroll
        for (int off = 1; off < 64; off <<= 1) l += __shfl_xor(l, off);
        if (lane == 0) atomicAdd(out, l * (1.0f / (float)B));
    }
}

extern "C" void kernel_launch(void* const* d_in, const int* in_sizes, int n_in,
                              void* d_out, int out_size, void* d_ws, size_t ws_size,
                              hipStream_t stream) {
    const float* x = (const float*)d_in[0];
    const float* y = (const float*)d_in[1];
    const float* W = (const float*)d_in[2];
    const float* s = (const float*)d_in[3];
    float* ws = (float*)d_ws;
    float* out = (float*)d_out;

    unsigned short* xfrag = (unsigned short*)(ws + OFF_XFRAG);
    unsigned short* wfrag = (unsigned short*)(ws + OFF_WFRAG);
    unsigned short* gfrag = (unsigned short*)(ws + OFF_GFRAG);
    unsigned int* label = (unsigned int*)(ws + OFF_LABEL);
    float* zlab = ws + OFF_ZLAB;
    float* psum = ws + OFF_PSUM;

    k_prep<<<576, 256, 0, stream>>>(x, W, y, xfrag, wfrag, gfrag, label, out);
    // grid.x = class-group (XCD-pinned), grid.y = b-tile
    k_logits_fused<<<dim3(C / 8, B / 64), 256, 0, stream>>>(xfrag, wfrag, gfrag,
                                                            label, s, psum, zlab);
    k_final<<<16, 256, 0, stream>>>(psum, zlab, out);
}

// Round 18
// 21.188 us; speedup vs baseline: 1.0968x; 1.0489x over previous
//
#include <hip/hip_runtime.h>
#include <hip/hip_bf16.h>
#include <math.h>

#define B 1024
#define C 512
#define S 32
#define E 128

typedef __attribute__((ext_vector_type(8))) short bf16x8;
typedef __attribute__((ext_vector_type(4))) float f32x4;

// ---------------------------------------------------------------------------
// Workspace layout (float units):
//   xfrag  : bf16 [B/16][4 kt][64 lane][8 j]   @ f0        (65536 f)
//   wfrag  : bf16 [C][4 kt][2 mt][64][8]       @ f65536    (1048576 f)
//   gfrag  : bf16 [C][2 mt][64][8]             @ f1114112  (262144 f)
//   label  : u32 [B]                           @ f1376256  (1024)
//   zlab   : f32 [B]                           @ f1377280  (1024)
//   psum   : f32 [64 cblk][B]                  @ f1378304  (65536)
// Fragment mapping (mfma_f32_16x16x32_bf16 A/B operand):
//   frag[j] = M[row = lane&15][k = 4*(lane>>4) + (j&3) + 16*(j>>2)]
// D mapping: D[row = 4*(lane>>4)+r][col = lane&15]
// z = s*logit in [0, ~8.9] -> exp safe without max-subtraction.
// ---------------------------------------------------------------------------
#define OFF_XFRAG  0
#define OFF_WFRAG  65536
#define OFF_GFRAG  1114112
#define OFF_LABEL  1376256
#define OFF_ZLAB   1377280
#define OFF_PSUM   1378304

// Native bf16 convert (RNE) — compiler emits v_cvt_pk_bf16_f32 for pairs
// (guide T12/m240: plain casts vectorize; hand-written cvt asm is what hurts).
__device__ inline unsigned short f2bf(float f) {
    __hip_bfloat16 h = __float2bfloat16(f);
    return *reinterpret_cast<unsigned short*>(&h);
}

// Fused prep: blocks [0,64) = x tiles (16 rows each) + label extraction;
// blocks [64,576) = one class each (normalize W, pack frags, Gram via MFMA).
// Block 0 also zeroes out[0] (k_final atomics accumulate into it later).
__global__ __launch_bounds__(256) void k_prep(const float* __restrict__ x,
                                              const float* __restrict__ W,
                                              const float* __restrict__ y,
                                              unsigned short* __restrict__ xfrag,
                                              unsigned short* __restrict__ wfrag,
                                              unsigned short* __restrict__ gfrag,
                                              unsigned int* __restrict__ label,
                                              float* __restrict__ out) {
    __shared__ float sM[32][132];
    __shared__ int4 wf[512];
    int t = threadIdx.x;
    int blk = blockIdx.x;
    if (blk == 0 && t == 0) out[0] = 0.f;
    if (blk < 64) {
        const float4* gx = reinterpret_cast<const float4*>(x + (size_t)blk * 16 * 128);
        #pragma unroll
        for (int i = 0; i < 2; ++i) {
            int ci = t + 256 * i;
            *reinterpret_cast<float4*>(&sM[ci >> 5][(ci & 31) << 2]) = gx[ci];
        }
        __syncthreads();
        int r = t >> 4, j = t & 15;
        float ss = 0.f;
        #pragma unroll
        for (int i = 0; i < 8; ++i) { float v = sM[r][j + 16 * i]; ss += v * v; }
        #pragma unroll
        for (int m = 1; m < 16; m <<= 1) ss += __shfl_xor(ss, m, 16);
        float sc = 1.0f / fmaxf(sqrtf(ss), 1e-12f);
        #pragma unroll
        for (int i = 0; i < 8; ++i) sM[r][j + 16 * i] *= sc;
        __syncthreads();
        int kt = t >> 6, lane = t & 63;
        int row = lane & 15, k0 = kt * 32 + 4 * (lane >> 4);
        union { unsigned short u[8]; int4 v; } pk;
        #pragma unroll
        for (int g = 0; g < 2; ++g) {
            float4 rv = *reinterpret_cast<const float4*>(&sM[row][k0 + 16 * g]);
            pk.u[4 * g + 0] = f2bf(rv.x); pk.u[4 * g + 1] = f2bf(rv.y);
            pk.u[4 * g + 2] = f2bf(rv.z); pk.u[4 * g + 3] = f2bf(rv.w);
        }
        reinterpret_cast<int4*>(xfrag)[(size_t)blk * 256 + t] = pk.v;
        // ---- label extraction for rows blk*16 .. blk*16+15 ----
        const float4* yr = reinterpret_cast<const float4*>(y + (size_t)(blk * 16 + r) * C);
        int idx = 0;
        #pragma unroll
        for (int k = 0; k < 8; ++k) {
            float4 v = yr[j + 16 * k];
            int base = (j + 16 * k) * 4;
            if (v.x > 0.5f) idx = base;
            if (v.y > 0.5f) idx = base + 1;
            if (v.z > 0.5f) idx = base + 2;
            if (v.w > 0.5f) idx = base + 3;
        }
        #pragma unroll
        for (int m = 1; m < 16; m <<= 1) idx = max(idx, __shfl_xor(idx, m, 16));
        if (j == 0) label[blk * 16 + r] = (unsigned int)idx;
    } else {
        int c = blk - 64;
        const float4* gw = reinterpret_cast<const float4*>(W + (size_t)c * S * E);
        #pragma unroll
        for (int i = 0; i < 4; ++i) {
            int ci = t + 256 * i;
            *reinterpret_cast<float4*>(&sM[ci >> 5][(ci & 31) << 2]) = gw[ci];
        }
        __syncthreads();
        int r = t >> 3, j = t & 7;
        float ss = 0.f;
        #pragma unroll
        for (int i = 0; i < 16; ++i) { float v = sM[r][j + 8 * i]; ss += v * v; }
        #pragma unroll
        for (int m = 1; m < 8; m <<= 1) ss += __shfl_xor(ss, m, 8);
        float sc = 1.0f / fmaxf(sqrtf(ss), 1e-12f);
        #pragma unroll
        for (int i = 0; i < 16; ++i) sM[r][j + 8 * i] *= sc;
        __syncthreads();
        int4* gwf = reinterpret_cast<int4*>(wfrag) + (size_t)c * 512;
        #pragma unroll
        for (int ci = t; ci < 512; ci += 256) {
            int kt = ci >> 7, mt = (ci >> 6) & 1, ln = ci & 63;
            int srow = mt * 16 + (ln & 15), k0 = kt * 32 + 4 * (ln >> 4);
            union { unsigned short u[8]; int4 v; } pk;
            #pragma unroll
            for (int g = 0; g < 2; ++g) {
                float4 rv = *reinterpret_cast<const float4*>(&sM[srow][k0 + 16 * g]);
                pk.u[4 * g + 0] = f2bf(rv.x); pk.u[4 * g + 1] = f2bf(rv.y);
                pk.u[4 * g + 2] = f2bf(rv.z); pk.u[4 * g + 3] = f2bf(rv.w);
            }
            wf[ci] = pk.v;
            gwf[ci] = pk.v;
        }
        __syncthreads();
        int w = t >> 6, lane = t & 63;
        if (w < 2) {
            const bf16x8* f = reinterpret_cast<const bf16x8*>(wf);
            f32x4 d0 = {0.f, 0.f, 0.f, 0.f}, d1 = d0;
            #pragma unroll
            for (int kt = 0; kt < 4; ++kt) {
                bf16x8 bnt = f[kt * 128 + w * 64 + lane];
                bf16x8 a0  = f[kt * 128 + lane];
                bf16x8 a1  = f[kt * 128 + 64 + lane];
                d0 = __builtin_amdgcn_mfma_f32_16x16x32_bf16(a0, bnt, d0, 0, 0, 0);
                d1 = __builtin_amdgcn_mfma_f32_16x16x32_bf16(a1, bnt, d1, 0, 0, 0);
            }
            union { unsigned short u[8]; int4 v; } pk;
            #pragma unroll
            for (int r2 = 0; r2 < 4; ++r2) {
                pk.u[r2]     = f2bf(d0[r2]);
                pk.u[r2 + 4] = f2bf(d1[r2]);
            }
            reinterpret_cast<int4*>(gfrag)[(size_t)c * 128 + w * 64 + lane] = pk.v;
        }
    }
}

// Fused logits+softmax-partials. Round-15 config (best: 21.9us): grid
// (64 class-groups, 16 b-tiles) = 1024 blocks -> 4 blocks/CU, VGPR 64,
// XCD-pinned class-groups (bid%8 == cy%8 -> each XCD's 640KB W/G slice is
// per-XCD-L2-resident despite the harness's 268MB L3-evicting poison fill
// between replays).
__global__ __launch_bounds__(256, 4) void k_logits_fused(const unsigned short* __restrict__ xfrag,
                                                         const unsigned short* __restrict__ wfrag,
                                                         const unsigned short* __restrict__ gfrag,
                                                         const unsigned int* __restrict__ label,
                                                         const float* __restrict__ s_ptr,
                                                         float* __restrict__ psum,
                                                         float* __restrict__ zlab) {
    __shared__ int4 smem[1024];       // 16KB X tile
    __shared__ float s_ps[4][4][16];  // per-wave psum partials
    int t = threadIdx.x;
    int w = t >> 6, lane = t & 63;
    int cy = blockIdx.x;              // class-group (XCD-pinned)
    int b0 = blockIdx.y * 64;         // b-tile
    int cbase = cy * 8;
    float s = s_ptr[0];

    const int4* gX = reinterpret_cast<const int4*>(xfrag) + (size_t)(b0 >> 4) * 256;
    #pragma unroll
    for (int i = 0; i < 4; ++i) smem[t + 256 * i] = gX[t + 256 * i];
    int labl[4];
    if (lane < 16) {
        #pragma unroll
        for (int bt = 0; bt < 4; ++bt) labl[bt] = (int)label[b0 + bt * 16 + lane];
    }
    __syncthreads();
    const bf16x8* fX = reinterpret_cast<const bf16x8*>(smem);  // [bt][kt][64]

    float psacc[4] = {0.f, 0.f, 0.f, 0.f};
    for (int it = 0; it < 2; ++it) {
        int c = cbase + it * 4 + w;
        const bf16x8* gW = reinterpret_cast<const bf16x8*>(wfrag) + (size_t)c * 512;
        const bf16x8* gG = reinterpret_cast<const bf16x8*>(gfrag) + (size_t)c * 128;
        bf16x8 a[4][2];
        #pragma unroll
        for (int kt = 0; kt < 4; ++kt) {
            a[kt][0] = gW[kt * 128 + lane];
            a[kt][1] = gW[kt * 128 + 64 + lane];
        }
        f32x4 acc[2][4];
        #pragma unroll
        for (int m = 0; m < 2; ++m)
            #pragma unroll
            for (int bt = 0; bt < 4; ++bt) acc[m][bt] = (f32x4){0.f, 0.f, 0.f, 0.f};
        #pragma unroll
        for (int kt = 0; kt < 4; ++kt) {
            #pragma unroll
            for (int bt = 0; bt < 4; ++bt) {
                bf16x8 bv = fX[bt * 256 + kt * 64 + lane];
                acc[0][bt] = __builtin_amdgcn_mfma_f32_16x16x32_bf16(a[kt][0], bv, acc[0][bt], 0, 0, 0);
                acc[1][bt] = __builtin_amdgcn_mfma_f32_16x16x32_bf16(a[kt][1], bv, acc[1][bt], 0, 0, 0);
            }
        }
        bf16x8 g0 = gG[lane];
        bf16x8 g1 = gG[64 + lane];
        #pragma unroll
        for (int bt = 0; bt < 4; ++bt) {
            union { unsigned short u[8]; bf16x8 v; } p;
            #pragma unroll
            for (int r = 0; r < 4; ++r) {
                p.u[r]     = f2bf(acc[0][bt][r]);
                p.u[r + 4] = f2bf(acc[1][bt][r]);
            }
            f32x4 h0 = {0.f, 0.f, 0.f, 0.f}, h1 = h0;
            h0 = __builtin_amdgcn_mfma_f32_16x16x32_bf16(g0, p.v, h0, 0, 0, 0);
            h1 = __builtin_amdgcn_mfma_f32_16x16x32_bf16(g1, p.v, h1, 0, 0, 0);
            float n = 0.f, q = 0.f;
            #pragma unroll
            for (int r = 0; r < 4; ++r) {
                n += acc[0][bt][r] * acc[0][bt][r] + acc[1][bt][r] * acc[1][bt][r];
                q += acc[0][bt][r] * h0[r] + acc[1][bt][r] * h1[r];
            }
            n += __shfl_xor(n, 16); n += __shfl_xor(n, 32);
            q += __shfl_xor(q, 16); q += __shfl_xor(q, 32);
            if (lane < 16) {
                float z = s * (n / fmaxf(sqrtf(q), 1e-12f));
                psacc[bt] += __expf(z);
                if (labl[bt] == c) zlab[b0 + bt * 16 + lane] = z;
            }
        }
    }
    if (lane < 16) {
        #pragma unroll
        for (int bt = 0; bt < 4; ++bt) s_ps[w][bt][lane] = psacc[bt];
    }
    __syncthreads();
    if (t < 64) {
        int bt = t >> 4, l = t & 15;
        float v = s_ps[0][bt][l] + s_ps[1][bt][l] + s_ps[2][bt][l] + s_ps[3][bt][l];
        psum[(size_t)cy * B + b0 + bt * 16 + l] = v;
    }
}

// Merged final: 16 blocks; block handles 64 rows. Wave w sums partials
// p in [16w, 16w+16) (wave-coalesced 256B reads), LDS combine, and the
// block's partial of mean(log(se) - zlab) is atomicAdd'ed into out[0]
// (16 atomics total; out zeroed by k_prep).
__global__ __launch_bounds__(256) void k_final(const float* __restrict__ psum,
                                               const float* __restrict__ zlab,
                                               float* __restrict__ out) {
    __shared__ float sacc[4][64];
    int t = threadIdx.x, w = t >> 6, lane = t & 63;
    int row = blockIdx.x * 64 + lane;
    float se = 0.f;
    #pragma unroll
    for (int i = 0; i < 16; ++i) {
        int p = w * 16 + i;
        se += psum[(size_t)p * B + row];
    }
    sacc[w][lane] = se;
    __syncthreads();
    if (w == 0) {
        float tot = sacc[0][lane] + sacc[1][lane] + sacc[2][lane] + sacc[3][lane];
        float l = logf(tot) - zlab[row];
        #pragma unroll
        for (int off = 1; off < 64; off <<= 1) l += __shfl_xor(l, off);
        if (lane == 0) atomicAdd(out, l * (1.0f / (float)B));
    }
}

extern "C" void kernel_launch(void* const* d_in, const int* in_sizes, int n_in,
                              void* d_out, int out_size, void* d_ws, size_t ws_size,
                              hipStream_t stream) {
    const float* x = (const float*)d_in[0];
    const float* y = (const float*)d_in[1];
    const float* W = (const float*)d_in[2];
    const float* s = (const float*)d_in[3];
    float* ws = (float*)d_ws;
    float* out = (float*)d_out;

    unsigned short* xfrag = (unsigned short*)(ws + OFF_XFRAG);
    unsigned short* wfrag = (unsigned short*)(ws + OFF_WFRAG);
    unsigned short* gfrag = (unsigned short*)(ws + OFF_GFRAG);
    unsigned int* label = (unsigned int*)(ws + OFF_LABEL);
    float* zlab = ws + OFF_ZLAB;
    float* psum = ws + OFF_PSUM;

    k_prep<<<576, 256, 0, stream>>>(x, W, y, xfrag, wfrag, gfrag, label, out);
    // grid.x = class-group (XCD-pinned), grid.y = b-tile
    k_logits_fused<<<dim3(C / 8, B / 64), 256, 0, stream>>>(xfrag, wfrag, gfrag,
                                                            label, s, psum, zlab);
    k_final<<<16, 256, 0, stream>>>(psum, zlab, out);
}